// Round 1
// 116.964 us; speedup vs baseline: 1.0069x; 1.0069x over previous
//
#include <hip/hip_runtime.h>
#include <hip/hip_bf16.h>

typedef __bf16 bf16x8 __attribute__((ext_vector_type(8)));
typedef float f32x4 __attribute__((ext_vector_type(4)));

#define F_IN 128
#define HF 32        // H * F_OUT
#define LBM_WORDS 4096  // 16 KiB LDS bitmask capacity (N up to 131072)

__device__ inline bf16x8 cvt8(float4 a, float4 b) {
    bf16x8 r;
    r[0] = (__bf16)a.x; r[1] = (__bf16)a.y; r[2] = (__bf16)a.z; r[3] = (__bf16)a.w;
    r[4] = (__bf16)b.x; r[5] = (__bf16)b.y; r[6] = (__bf16)b.z; r[7] = (__bf16)b.w;
    return r;
}

// Kernel 1: build a bitmask of nodes that appear as a source of >=1 edge.
// LDS-aggregated: 1.6M scatter writes become on-CU LDS atomics; global traffic
// is the coalesced edge read (6.4 MB) + <=grid*nwords coalesced atomicOr.
__global__ __launch_bounds__(256) void mask_build_kernel(
    const int* __restrict__ src, int E,
    unsigned int* __restrict__ bm, int nwords) {
    __shared__ unsigned int lbm[LBM_WORDS];
    const int tid = threadIdx.x;
    const int gtid = blockIdx.x * blockDim.x + tid;
    const int gstride = gridDim.x * blockDim.x;

    if (nwords <= LBM_WORDS) {
        for (int i = tid; i < nwords; i += blockDim.x) lbm[i] = 0u;
        __syncthreads();

        const int nvec = E >> 2;  // int4 chunks
        const int4* src4 = (const int4*)src;
        for (int i = gtid; i < nvec; i += gstride) {
            int4 v = src4[i];
            atomicOr(&lbm[((unsigned)v.x) >> 5], 1u << (v.x & 31));
            atomicOr(&lbm[((unsigned)v.y) >> 5], 1u << (v.y & 31));
            atomicOr(&lbm[((unsigned)v.z) >> 5], 1u << (v.z & 31));
            atomicOr(&lbm[((unsigned)v.w) >> 5], 1u << (v.w & 31));
        }
        for (int i = (nvec << 2) + gtid; i < E; i += gstride) {  // tail
            int s = src[i];
            atomicOr(&lbm[((unsigned)s) >> 5], 1u << (s & 31));
        }
        __syncthreads();

        for (int i = tid; i < nwords; i += blockDim.x) {
            unsigned int w = lbm[i];
            if (w) atomicOr(&bm[i], w);  // skip zero words (~14% at E/N=16)
        }
    } else {
        // Safety fallback for N beyond LDS capacity: direct global atomics.
        for (int i = gtid; i < E; i += gstride) {
            int s = src[i];
            atomicOr(&bm[((unsigned)s) >> 5], 1u << (s & 31));
        }
    }
}

// Kernel 2: out[n,:] = (h_in[n,:] @ W^T + b) * (bit(n) ? 1 : 0)
// fp32 in/out; bf16 MFMA internally (2%-relative threshold covers rounding).
// Wave handles 32 nodes (2 m-tiles of 16), block = 4 waves = 128 nodes.
__global__ __launch_bounds__(256) void gat_gemm_kernel(
    const float* __restrict__ h_in, const float* __restrict__ W,
    const float* __restrict__ b, const unsigned int* __restrict__ bm,
    float* __restrict__ out, int N) {
    const int tid  = threadIdx.x;
    const int lane = tid & 63;
    const int wave = tid >> 6;
    const int q = lane >> 4;   // k-quad for A/B, row-quad for C/D
    const int c = lane & 15;   // m for A, n for B, col for C/D

    const int node_base = blockIdx.x * 128 + wave * 32;
    if (node_base >= N) return;

    // B fragments: B[k][n] = W[n][k]; W is [32][128] row-major (out x in).
    // Lane needs W[nt*16+c][ks*32 + q*8 .. +7] -> 8 consecutive floats.
    bf16x8 bfrag[2][4];
#pragma unroll
    for (int nt = 0; nt < 2; ++nt) {
        const float* wp = W + (nt * 16 + c) * F_IN + q * 8;
#pragma unroll
        for (int ks = 0; ks < 4; ++ks) {
            float4 f0 = *(const float4*)(wp + ks * 32);
            float4 f1 = *(const float4*)(wp + ks * 32 + 4);
            bfrag[nt][ks] = cvt8(f0, f1);
        }
    }

    // A fragments: A[m][k] = h_in[node_base + mt*16 + c][ks*32 + q*8 .. +7]
    bf16x8 afrag[2][4];
#pragma unroll
    for (int mt = 0; mt < 2; ++mt) {
        int row = node_base + mt * 16 + c;
        if (row > N - 1) row = N - 1;  // clamp; stores are guarded
        const float* hp = h_in + (long)row * F_IN + q * 8;
#pragma unroll
        for (int ks = 0; ks < 4; ++ks) {
            float4 f0 = *(const float4*)(hp + ks * 32);
            float4 f1 = *(const float4*)(hp + ks * 32 + 4);
            afrag[mt][ks] = cvt8(f0, f1);
        }
    }

    f32x4 acc[2][2] = {{{0.f, 0.f, 0.f, 0.f}, {0.f, 0.f, 0.f, 0.f}},
                       {{0.f, 0.f, 0.f, 0.f}, {0.f, 0.f, 0.f, 0.f}}};
#pragma unroll
    for (int ks = 0; ks < 4; ++ks)
#pragma unroll
        for (int mt = 0; mt < 2; ++mt)
#pragma unroll
            for (int nt = 0; nt < 2; ++nt)
                acc[mt][nt] = __builtin_amdgcn_mfma_f32_16x16x32_bf16(
                    afrag[mt][ks], bfrag[nt][ks], acc[mt][nt], 0, 0, 0);

    const float bias0 = b[c];
    const float bias1 = b[c + 16];

    // node_base is 32-aligned, so the wave's 32 output rows live in ONE
    // bitmask dword -> wave-uniform scalar load, bit index = row - node_base.
    const unsigned int mword = bm[node_base >> 5];

    // C/D layout: col = lane&15, row = q*4 + reg
#pragma unroll
    for (int mt = 0; mt < 2; ++mt) {
        int rowb = node_base + mt * 16 + q * 4;
#pragma unroll
        for (int r = 0; r < 4; ++r) {
            int row = rowb + r;
            if (row < N) {
                float s = ((mword >> (mt * 16 + q * 4 + r)) & 1u) ? 1.0f : 0.0f;
                out[(long)row * HF + c]      = (acc[mt][0][r] + bias0) * s;
                out[(long)row * HF + 16 + c] = (acc[mt][1][r] + bias1) * s;
            }
        }
    }
}

extern "C" void kernel_launch(void* const* d_in, const int* in_sizes, int n_in,
                              void* d_out, int out_size, void* d_ws, size_t ws_size,
                              hipStream_t stream) {
    // Inputs (setup_inputs order): h_in, W, b, a_src, a_tgt, edge_index
    const float* h_in = (const float*)d_in[0];
    const float* W    = (const float*)d_in[1];
    const float* b    = (const float*)d_in[2];
    const int* edge_index = (const int*)d_in[5];

    const int N = in_sizes[0] / F_IN;
    const int E = in_sizes[5] / 2;  // edge_index is [2, E]; row 0 = src

    unsigned int* bm = (unsigned int*)d_ws;  // bitmask scratch
    const int nwords = (N + 31) / 32;

    hipMemsetAsync(bm, 0, (size_t)nwords * sizeof(unsigned int), stream);

    mask_build_kernel<<<128, 256, 0, stream>>>(edge_index, E, bm, nwords);

    int gb = (N + 127) / 128;
    gat_gemm_kernel<<<gb, 256, 0, stream>>>(h_in, W, b, bm,
                                            (float*)d_out, N);
}

// Round 2
// 114.311 us; speedup vs baseline: 1.0303x; 1.0232x over previous
//
#include <hip/hip_runtime.h>
#include <hip/hip_bf16.h>

typedef __bf16 bf16x8 __attribute__((ext_vector_type(8)));
typedef float f32x4 __attribute__((ext_vector_type(4)));

#define F_IN 128
#define HF 32           // H * F_OUT
#define LBM_WORDS 4096  // 16 KiB LDS bitmask chunk (covers N<=131072 in one chunk)
#define MASK_BLOCKS 128 // partial-bitmap count; gemm OR-reduces exactly this many

// Kernel 1: each block builds a PRIVATE bitmask of source nodes in LDS and
// writes it to its own workspace slice with plain coalesced stores.
// No memset needed (slices fully overwritten), no global atomics at all.
__global__ __launch_bounds__(256) void mask_partial_kernel(
    const int* __restrict__ src, int E,
    unsigned int* __restrict__ pbm, int pstride, int nwords) {
    __shared__ unsigned int lbm[LBM_WORDS];
    const int tid = threadIdx.x;
    unsigned int* dst = pbm + (long)blockIdx.x * pstride;

    const int gtid = blockIdx.x * 256 + tid;
    const int gstride = gridDim.x * 256;
    const int nvec = E >> 2;
    const int4* src4 = (const int4*)src;

    for (int cbase = 0; cbase < nwords; cbase += LBM_WORDS) {
        const int cwords = min(nwords - cbase, LBM_WORDS);
        for (int i = tid; i < cwords; i += 256) lbm[i] = 0u;
        __syncthreads();

        if (nwords <= LBM_WORDS) {
            // Fast path: whole mask fits one chunk, no range filtering.
            for (int i = gtid; i < nvec; i += gstride) {
                int4 v = src4[i];
                atomicOr(&lbm[((unsigned)v.x) >> 5], 1u << (v.x & 31));
                atomicOr(&lbm[((unsigned)v.y) >> 5], 1u << (v.y & 31));
                atomicOr(&lbm[((unsigned)v.z) >> 5], 1u << (v.z & 31));
                atomicOr(&lbm[((unsigned)v.w) >> 5], 1u << (v.w & 31));
            }
            for (int i = (nvec << 2) + gtid; i < E; i += gstride) {
                int s = src[i];
                atomicOr(&lbm[((unsigned)s) >> 5], 1u << (s & 31));
            }
        } else {
            // Generic fallback: re-scan edges per chunk with range filter.
            const unsigned int lo = (unsigned)cbase << 5;
            const unsigned int hi = lo + ((unsigned)cwords << 5);
            for (int i = gtid; i < nvec; i += gstride) {
                int4 v = src4[i];
                if ((unsigned)v.x >= lo && (unsigned)v.x < hi)
                    atomicOr(&lbm[(((unsigned)v.x) >> 5) - cbase], 1u << (v.x & 31));
                if ((unsigned)v.y >= lo && (unsigned)v.y < hi)
                    atomicOr(&lbm[(((unsigned)v.y) >> 5) - cbase], 1u << (v.y & 31));
                if ((unsigned)v.z >= lo && (unsigned)v.z < hi)
                    atomicOr(&lbm[(((unsigned)v.z) >> 5) - cbase], 1u << (v.z & 31));
                if ((unsigned)v.w >= lo && (unsigned)v.w < hi)
                    atomicOr(&lbm[(((unsigned)v.w) >> 5) - cbase], 1u << (v.w & 31));
            }
            for (int i = (nvec << 2) + gtid; i < E; i += gstride) {
                unsigned int s = (unsigned)src[i];
                if (s >= lo && s < hi)
                    atomicOr(&lbm[(s >> 5) - cbase], 1u << (s & 31));
            }
        }
        __syncthreads();

        for (int i = tid; i < cwords; i += 256) dst[cbase + i] = lbm[i];
        __syncthreads();  // stores read lbm; must complete before next zero
    }
}

// Kernel 2: out[n,:] = (h_in[n,:] @ W^T + b) * (bit(n) ? 1 : 0)
// fp32 in/out; bf16 MFMA internally (2%-relative threshold covers rounding).
// Wave handles 32 nodes (2 m-tiles of 16), block = 4 waves = 128 nodes.
// The wave's 32 nodes live in ONE bitmask word; its value is the OR of the
// 128 per-block partials, reduced in-wave (loads issued early, latency-hidden).
__global__ __launch_bounds__(256) void gat_gemm_kernel(
    const float* __restrict__ h_in, const float* __restrict__ W,
    const float* __restrict__ b, const unsigned int* __restrict__ pbm,
    int pstride, float* __restrict__ out, int N) {
    const int tid  = threadIdx.x;
    const int lane = tid & 63;
    const int wave = tid >> 6;
    const int q = lane >> 4;   // k-quad for A/B, row-quad for C/D
    const int c = lane & 15;   // m for A, n for B, col for C/D

    const int node_base = blockIdx.x * 128 + wave * 32;
    if (node_base >= N) return;
    const int wi = node_base >> 5;

    // Issue partial-mask loads first; they complete under the A/B load shadow.
    const unsigned int pm0 = pbm[(long)lane * pstride + wi];
    const unsigned int pm1 = pbm[(long)(lane + 64) * pstride + wi];

    // A fragments: A[m][k] = h_in[node_base + mt*16 + c][ks*32 + q*8 .. +7]
    bf16x8 afrag[2][4];
#pragma unroll
    for (int mt = 0; mt < 2; ++mt) {
        int row = node_base + mt * 16 + c;
        if (row > N - 1) row = N - 1;  // clamp; stores are guarded
        const float* hp = h_in + (long)row * F_IN + q * 8;
#pragma unroll
        for (int ks = 0; ks < 4; ++ks) {
            float4 f0 = *(const float4*)(hp + ks * 32);
            float4 f1 = *(const float4*)(hp + ks * 32 + 4);
            bf16x8 r;
            r[0] = (__bf16)f0.x; r[1] = (__bf16)f0.y; r[2] = (__bf16)f0.z; r[3] = (__bf16)f0.w;
            r[4] = (__bf16)f1.x; r[5] = (__bf16)f1.y; r[6] = (__bf16)f1.z; r[7] = (__bf16)f1.w;
            afrag[mt][ks] = r;
        }
    }

    // B fragments: B[k][n] = W[n][k]; W is [32][128] row-major (out x in).
    bf16x8 bfrag[2][4];
#pragma unroll
    for (int nt = 0; nt < 2; ++nt) {
        const float* wp = W + (nt * 16 + c) * F_IN + q * 8;
#pragma unroll
        for (int ks = 0; ks < 4; ++ks) {
            float4 f0 = *(const float4*)(wp + ks * 32);
            float4 f1 = *(const float4*)(wp + ks * 32 + 4);
            bf16x8 r;
            r[0] = (__bf16)f0.x; r[1] = (__bf16)f0.y; r[2] = (__bf16)f0.z; r[3] = (__bf16)f0.w;
            r[4] = (__bf16)f1.x; r[5] = (__bf16)f1.y; r[6] = (__bf16)f1.z; r[7] = (__bf16)f1.w;
            bfrag[nt][ks] = r;
        }
    }

    f32x4 acc[2][2] = {{{0.f, 0.f, 0.f, 0.f}, {0.f, 0.f, 0.f, 0.f}},
                       {{0.f, 0.f, 0.f, 0.f}, {0.f, 0.f, 0.f, 0.f}}};
#pragma unroll
    for (int ks = 0; ks < 4; ++ks)
#pragma unroll
        for (int mt = 0; mt < 2; ++mt)
#pragma unroll
            for (int nt = 0; nt < 2; ++nt)
                acc[mt][nt] = __builtin_amdgcn_mfma_f32_16x16x32_bf16(
                    afrag[mt][ks], bfrag[nt][ks], acc[mt][nt], 0, 0, 0);

    // OR-reduce the 128 partial words across the wave (6 x shfl_xor).
    unsigned int mw = pm0 | pm1;
#pragma unroll
    for (int off = 32; off; off >>= 1)
        mw |= (unsigned int)__shfl_xor((int)mw, off);

    const float bias0 = b[c];
    const float bias1 = b[c + 16];

    // C/D layout: col = lane&15, row = q*4 + reg
#pragma unroll
    for (int mt = 0; mt < 2; ++mt) {
        int rowb = node_base + mt * 16 + q * 4;
#pragma unroll
        for (int r = 0; r < 4; ++r) {
            int row = rowb + r;
            if (row < N) {
                float s = ((mw >> (mt * 16 + q * 4 + r)) & 1u) ? 1.0f : 0.0f;
                out[(long)row * HF + c]      = (acc[mt][0][r] + bias0) * s;
                out[(long)row * HF + 16 + c] = (acc[mt][1][r] + bias1) * s;
            }
        }
    }
}

extern "C" void kernel_launch(void* const* d_in, const int* in_sizes, int n_in,
                              void* d_out, int out_size, void* d_ws, size_t ws_size,
                              hipStream_t stream) {
    // Inputs (setup_inputs order): h_in, W, b, a_src, a_tgt, edge_index
    const float* h_in = (const float*)d_in[0];
    const float* W    = (const float*)d_in[1];
    const float* b    = (const float*)d_in[2];
    const int* edge_index = (const int*)d_in[5];

    const int N = in_sizes[0] / F_IN;   // in_sizes are element counts
    const int E = in_sizes[5] / 2;      // edge_index is [2, E]; row 0 = src

    const int nwords = (N + 31) / 32;
    const int pstride = (nwords + 63) & ~63;  // 256B-aligned slice stride
    unsigned int* pbm = (unsigned int*)d_ws;  // 128 * pstride * 4 bytes used

    mask_partial_kernel<<<MASK_BLOCKS, 256, 0, stream>>>(
        edge_index, E, pbm, pstride, nwords);

    int gb = (N + 127) / 128;
    gat_gemm_kernel<<<gb, 256, 0, stream>>>(h_in, W, b, pbm, pstride,
                                            (float*)d_out, N);
}